// Round 2
// baseline (7354.501 us; speedup 1.0000x reference)
//
#include <hip/hip_runtime.h>
#include <cstdint>
#include <cstddef>

constexpr int CC = 320;     // channels
constexpr int NN = 3136;    // tokens (56*56)
constexpr int BB = 2;       // batch
constexpr int RR = BB * NN; // 6272 rows
constexpr float BN_INV_F = 0.9999950000374997f; // 1/sqrt(1+1e-5)

// ---------------- weight transposes: (l, co, ci) -> (l, ci, co) ----------------
__global__ __launch_bounds__(256) void transpose6(
    const float* __restrict__ w0, const float* __restrict__ w1,
    const float* __restrict__ w2, const float* __restrict__ w3,
    const float* __restrict__ w4, const float* __restrict__ w5,
    float* __restrict__ out) {
  size_t e = (size_t)blockIdx.x * 256 + threadIdx.x;
  const size_t per = (size_t)6 * CC * CC;
  if (e >= 6 * per) return;
  int m = (int)(e / per);
  size_t r = e % per;
  int l = (int)(r / (CC * CC));
  int q = (int)(r % (CC * CC));
  int ci = q / CC, co = q % CC;
  const float* src = (m == 0) ? w0 : (m == 1) ? w1 : (m == 2) ? w2
                   : (m == 3) ? w3 : (m == 4) ? w4 : w5;
  out[e] = src[(size_t)l * CC * CC + (size_t)co * CC + ci];
}

__global__ __launch_bounds__(256) void transpose_gc(const float* __restrict__ w,
                                                    float* __restrict__ out) {
  size_t e = (size_t)blockIdx.x * 256 + threadIdx.x;
  const size_t tot = (size_t)6 * 2 * CC * CC;
  if (e >= tot) return;
  int l = (int)(e / (2 * CC * CC));
  int q = (int)(e % (2 * CC * CC));
  int ci = q / CC, co = q % CC; // ci in [0,640)
  out[e] = w[(size_t)l * CC * 2 * CC + (size_t)co * 2 * CC + ci];
}

// ---------------- direct conv + bias + BN (+relu) ----------------
template <int CIN, int IH, int IW, int OC, int OH, int OW, int STRIDE, bool RELU>
__global__ __launch_bounds__(256) void conv_bn(
    const float* __restrict__ x, const float* __restrict__ w,
    const float* __restrict__ cb, const float* __restrict__ g,
    const float* __restrict__ bt, float* __restrict__ out) {
  int t = blockIdx.x * 256 + threadIdx.x;
  if (t >= BB * OC * OH * OW) return;
  int ow = t % OW;
  int r = t / OW;
  int oh = r % OH; r /= OH;
  int oc = r % OC;
  int b = r / OC;
  int ih0 = oh * STRIDE - 1, iw0 = ow * STRIDE - 1;
  const float* wp = w + (size_t)oc * CIN * 9;
  const float* xb = x + (size_t)b * CIN * IH * IW;
  float acc = 0.f;
  for (int ic = 0; ic < CIN; ic++) {
    const float* xc = xb + (size_t)ic * IH * IW;
    const float* wc = wp + ic * 9;
#pragma unroll
    for (int kh = 0; kh < 3; kh++) {
      int ih = ih0 + kh;
      if (ih < 0 || ih >= IH) continue;
      const float* xr = xc + (size_t)ih * IW;
#pragma unroll
      for (int kw = 0; kw < 3; kw++) {
        int iw = iw0 + kw;
        if (iw < 0 || iw >= IW) continue;
        acc = fmaf(xr[iw], wc[kh * 3 + kw], acc);
      }
    }
  }
  float y = (acc + cb[oc]) * (BN_INV_F * g[oc]) + bt[oc];
  if (RELU) y = fmaxf(y, 0.f);
  out[t] = y;
}

// ---------------- expmap0 over channel dim + pos embed; (B,C,N) -> tokens (B,N,C) ----------------
__global__ __launch_bounds__(CC) void expmap_kernel(const float* __restrict__ h,
                                                    const float* __restrict__ pos,
                                                    float* __restrict__ X) {
  int bn = blockIdx.x;
  int b = bn / NN, n = bn % NN;
  int c = threadIdx.x;
  float u = h[((size_t)(b * CC + c)) * NN + n] + pos[(size_t)c * NN + n];
  float v = (c == 0) ? 0.f : u * u;
#pragma unroll
  for (int o = 32; o > 0; o >>= 1) v += __shfl_down(v, o, 64);
  __shared__ float red[5];
  __shared__ float fac[2];
  if ((c & 63) == 0) red[c >> 6] = v;
  __syncthreads();
  if (c == 0) {
    float s = red[0] + red[1] + red[2] + red[3] + red[4];
    float nrm = sqrtf(fmaxf(s, 1e-8f));
    fac[0] = coshf(nrm);
    fac[1] = sinhf(nrm) / nrm;
  }
  __syncthreads();
  X[(size_t)bn * CC + c] = (c == 0) ? fac[0] : fac[1] * u;
}

// ---------------- P permutation: V[n*C+c] = U[c*N+n]  (+ optional add[n*C+c]) ----------------
// U is the flat (N,C) token buffer reinterpreted as (C,N) row-major, per batch.
__global__ __launch_bounds__(256) void pperm_kernel(const float* __restrict__ U,
                                                    const float* __restrict__ add,
                                                    float* __restrict__ V) {
  __shared__ float t[64][65];
  int b = blockIdx.z;
  int n0 = blockIdx.x * 64;
  int c0 = blockIdx.y * 64;
  const float* Ub = U + (size_t)b * NN * CC;
  float* Vb = V + (size_t)b * NN * CC;
  const float* Ab = add ? add + (size_t)b * NN * CC : nullptr;
  int tx = threadIdx.x & 63;
  int ty = threadIdx.x >> 6; // 0..3
#pragma unroll
  for (int i = 0; i < 16; i++) {
    int c = ty * 16 + i;
    t[c][tx] = Ub[(size_t)(c0 + c) * NN + n0 + tx];
  }
  __syncthreads();
#pragma unroll
  for (int i = 0; i < 16; i++) {
    int n = ty * 16 + i;
    float v = t[tx][n];
    size_t o = (size_t)(n0 + n) * CC + c0 + tx;
    if (Ab) v += Ab[o];
    Vb[o] = v;
  }
}

// ---------------- GEMM: C[M,320] = relu(A[M,K]) @ WT[K,320] + bias ----------------
__global__ __launch_bounds__(256) void gemm_ll(const float* __restrict__ A,
                                               const float* __restrict__ BW,
                                               const float* __restrict__ bias,
                                               float* __restrict__ C, int M, int K) {
  __shared__ float As[16][68];
  __shared__ float Bs[16][64];
  int tid = threadIdx.x;
  int n0 = blockIdx.x * 64;
  int m0 = blockIdx.y * 64;
  int lm = tid >> 2;
  int lk = (tid & 3) << 2;
  int bk = tid >> 4;
  int bn = (tid & 15) << 2;
  int tm = (tid >> 4) << 2;
  int tn = (tid & 15) << 2;
  float acc[4][4] = {};
  for (int k0 = 0; k0 < K; k0 += 16) {
    float4 a = *(const float4*)(A + (size_t)(m0 + lm) * K + k0 + lk);
    a.x = fmaxf(a.x, 0.f); a.y = fmaxf(a.y, 0.f);
    a.z = fmaxf(a.z, 0.f); a.w = fmaxf(a.w, 0.f);
    As[lk + 0][lm] = a.x; As[lk + 1][lm] = a.y;
    As[lk + 2][lm] = a.z; As[lk + 3][lm] = a.w;
    *(float4*)&Bs[bk][bn] = *(const float4*)(BW + (size_t)(k0 + bk) * CC + n0 + bn);
    __syncthreads();
#pragma unroll
    for (int k = 0; k < 16; k++) {
      float4 av = *(const float4*)&As[k][tm];
      float4 bv = *(const float4*)&Bs[k][tn];
      float aa[4] = {av.x, av.y, av.z, av.w};
      float bb[4] = {bv.x, bv.y, bv.z, bv.w};
#pragma unroll
      for (int i = 0; i < 4; i++)
#pragma unroll
        for (int j = 0; j < 4; j++) acc[i][j] = fmaf(aa[i], bb[j], acc[i][j]);
    }
    __syncthreads();
  }
  float4 bv = *(const float4*)(bias + n0 + tn);
  float bb[4] = {bv.x, bv.y, bv.z, bv.w};
#pragma unroll
  for (int i = 0; i < 4; i++) {
    float4 o;
    o.x = acc[i][0] + bb[0]; o.y = acc[i][1] + bb[1];
    o.z = acc[i][2] + bb[2]; o.w = acc[i][3] + bb[3];
    *(float4*)(C + (size_t)(m0 + tm + i) * CC + n0 + tn) = o;
  }
}

// ---------------- Lorentz row normalization (+ optional residual) ----------------
__global__ __launch_bounds__(256) void lorentz_norm(const float* __restrict__ Y,
                                                    const float* __restrict__ logs, int l,
                                                    const float* __restrict__ res1,
                                                    float* __restrict__ out) {
  int lane = threadIdx.x & 63;
  size_t row = (size_t)blockIdx.x * 4 + (threadIdx.x >> 6);
  const float* y = Y + row * CC;
  float v[5];
  float ss = 0.f;
#pragma unroll
  for (int q = 0; q < 5; q++) {
    v[q] = y[q * 64 + lane];
    float z = v[q] * v[q];
    if (q == 0 && lane == 0) z = 0.f;
    ss += z;
  }
#pragma unroll
  for (int o = 32; o > 0; o >>= 1) ss += __shfl_down(ss, o, 64);
  ss = __shfl(ss, 0, 64);
  float y0 = __shfl(v[0], 0, 64);
  float scale = expf(logs[l]);
  float tmv = scale / (1.f + expf(-y0)) + 1.1f;
  float rf = sqrtf((tmv * tmv - 1.f) / fmaxf(ss, 1e-8f));
#pragma unroll
  for (int q = 0; q < 5; q++) {
    int c = q * 64 + lane;
    float o = (c == 0) ? tmv : v[q] * rf;
    if (res1) o += res1[row * CC + c];
    out[row * CC + c] = o;
  }
}

// ---------------- per-row squared norms ----------------
__global__ __launch_bounds__(256) void sq_kernel(const float* __restrict__ Y,
                                                 float* __restrict__ sq) {
  int lane = threadIdx.x & 63;
  size_t row = (size_t)blockIdx.x * 4 + (threadIdx.x >> 6);
  const float* y = Y + row * CC;
  float ss = 0.f;
#pragma unroll
  for (int q = 0; q < 5; q++) {
    float v = y[q * 64 + lane];
    ss += v * v;
  }
#pragma unroll
  for (int o = 32; o > 0; o >>= 1) ss += __shfl_down(ss, o, 64);
  if (lane == 0) sq[row] = ss;
}

// ---------------- distance tile: D[i,j] = sq_i + sq_j - 2 * Y_i . Y_j ----------------
__global__ __launch_bounds__(256) void dist_gemm(const float* __restrict__ Y,
                                                 const float* __restrict__ sq,
                                                 float* __restrict__ D) {
  __shared__ float As[16][68];
  __shared__ float Bs[16][68];
  int tid = threadIdx.x;
  int j0 = blockIdx.x * 64;
  int i0 = blockIdx.y * 64;
  int lr = tid >> 2;
  int lk = (tid & 3) << 2;
  int tm = (tid >> 4) << 2;
  int tn = (tid & 15) << 2;
  float acc[4][4] = {};
  for (int k0 = 0; k0 < CC; k0 += 16) {
    float4 a = *(const float4*)(Y + (size_t)(i0 + lr) * CC + k0 + lk);
    As[lk + 0][lr] = a.x; As[lk + 1][lr] = a.y;
    As[lk + 2][lr] = a.z; As[lk + 3][lr] = a.w;
    float4 b = *(const float4*)(Y + (size_t)(j0 + lr) * CC + k0 + lk);
    Bs[lk + 0][lr] = b.x; Bs[lk + 1][lr] = b.y;
    Bs[lk + 2][lr] = b.z; Bs[lk + 3][lr] = b.w;
    __syncthreads();
#pragma unroll
    for (int k = 0; k < 16; k++) {
      float4 av = *(const float4*)&As[k][tm];
      float4 bv = *(const float4*)&Bs[k][tn];
      float aa[4] = {av.x, av.y, av.z, av.w};
      float bb[4] = {bv.x, bv.y, bv.z, bv.w};
#pragma unroll
      for (int i = 0; i < 4; i++)
#pragma unroll
        for (int j = 0; j < 4; j++) acc[i][j] = fmaf(aa[i], bb[j], acc[i][j]);
    }
    __syncthreads();
  }
  float sqi[4], sqj[4];
#pragma unroll
  for (int i = 0; i < 4; i++) sqi[i] = sq[i0 + tm + i];
#pragma unroll
  for (int j = 0; j < 4; j++) sqj[j] = sq[j0 + tn + j];
#pragma unroll
  for (int i = 0; i < 4; i++) {
    float4 o;
    o.x = sqi[i] + sqj[0] - 2.f * acc[i][0];
    o.y = sqi[i] + sqj[1] - 2.f * acc[i][1];
    o.z = sqi[i] + sqj[2] - 2.f * acc[i][2];
    o.w = sqi[i] + sqj[3] - 2.f * acc[i][3];
    *(float4*)(D + (size_t)(i0 + tm + i) * NN + j0 + tn) = o;
  }
}

// ---------------- exact top-k (jax tie-break: dist asc, index asc), wave per row ----------------
template <int KT, int DIL>
__global__ __launch_bounds__(256) void topk_kernel(const float* __restrict__ D,
                                                   int* __restrict__ idxout) {
  int lane = threadIdx.x & 63;
  int row = blockIdx.x * 4 + (threadIdx.x >> 6); // row within one batch, [0, NN)
  const float* d = D + (size_t)row * NN;
  float ld[KT];
  int li[KT];
#pragma unroll
  for (int q = 0; q < KT; q++) { ld[q] = 3.4e38f; li[q] = 0x7FFFFFFF; }
  for (int t = 0; t < NN / 64; t++) {
    int j = t * 64 + lane;
    float x = d[j];
    if (x < ld[KT - 1]) {
      ld[KT - 1] = x;
      li[KT - 1] = j;
#pragma unroll
      for (int p = KT - 1; p > 0; p--) {
        if (ld[p] < ld[p - 1]) {
          float tf = ld[p]; ld[p] = ld[p - 1]; ld[p - 1] = tf;
          int ti = li[p]; li[p] = li[p - 1]; li[p - 1] = ti;
        }
      }
    }
  }
  // wave-wide merge: KT rounds of lexicographic argmin + pop
#pragma unroll 1
  for (int q = 0; q < KT; q++) {
    float bd = ld[0];
    int bi = li[0];
#pragma unroll
    for (int s = 32; s > 0; s >>= 1) {
      float od = __shfl_xor(bd, s, 64);
      int oi = __shfl_xor(bi, s, 64);
      if (od < bd || (od == bd && oi < bi)) { bd = od; bi = oi; }
    }
    if (ld[0] == bd && li[0] == bi) { // unique winner (j indices are unique)
#pragma unroll
      for (int p = 0; p < KT - 1; p++) { ld[p] = ld[p + 1]; li[p] = li[p + 1]; }
      ld[KT - 1] = 3.4e38f;
      li[KT - 1] = 0x7FFFFFFF;
    }
    if (lane == 0 && (q % DIL) == 0) idxout[(size_t)row * 9 + q / DIL] = bi;
  }
}

// ---------------- neighbor max + concat [f, max_j f_j - f_i] ----------------
__global__ __launch_bounds__(CC) void gather_max_cat(const float* __restrict__ Y,
                                                     const int* __restrict__ idx,
                                                     float* __restrict__ cat) {
  int bn = blockIdx.x;
  int c = threadIdx.x;
  int b = bn / NN;
  float yc = Y[(size_t)bn * CC + c];
  const int* ip = idx + (size_t)bn * 9;
  float mx = -3.4e38f;
#pragma unroll
  for (int q = 0; q < 9; q++) {
    int j = ip[q];
    mx = fmaxf(mx, Y[((size_t)b * NN + j) * CC + c]);
  }
  cat[(size_t)bn * 2 * CC + c] = yc;
  cat[(size_t)bn * 2 * CC + CC + c] = mx - yc;
}

// ---------------- pooling + head ----------------
__global__ __launch_bounds__(CC) void pool_kernel(const float* __restrict__ X,
                                                  float* __restrict__ pooled) {
  int b = blockIdx.y;
  int chunk = blockIdx.x;
  int c = threadIdx.x;
  const float* p = X + ((size_t)b * NN + (size_t)chunk * 64) * CC + c;
  float s = 0.f;
#pragma unroll
  for (int q = 0; q < 64; q++) s += p[(size_t)q * CC];
  atomicAdd(&pooled[b * CC + c], s);
}

__global__ __launch_bounds__(256) void head_kernel(const float* __restrict__ pooled,
                                                   const float* __restrict__ clsw,
                                                   const float* __restrict__ hb,
                                                   float* __restrict__ out) {
  int t = blockIdx.x * 256 + threadIdx.x;
  if (t >= BB * 1000) return;
  int b = t / 1000, k = t % 1000;
  const float* pw = pooled + b * CC;
  const float* cw = clsw + (size_t)k * CC;
  float acc = 0.f;
  for (int c = 0; c < CC; c++) {
    float sgn = (c == 0) ? -1.f : 1.f;
    acc = fmaf(pw[c] * sgn, cw[c], acc);
  }
  out[t] = 2.f + 2.f * (acc * (1.f / 3136.f)) + hb[k];
}

// ---------------- launch ----------------
extern "C" void kernel_launch(void* const* d_in, const int* in_sizes, int n_in,
                              void* d_out, int out_size, void* d_ws, size_t ws_size,
                              hipStream_t stream) {
  const float* x = (const float*)d_in[0];
  const float* c1w = (const float*)d_in[1];
  const float* c1b = (const float*)d_in[2];
  const float* bn1g = (const float*)d_in[3];
  const float* bn1b = (const float*)d_in[4];
  const float* c2w = (const float*)d_in[5];
  const float* c2b = (const float*)d_in[6];
  const float* bn2g = (const float*)d_in[7];
  const float* bn2b = (const float*)d_in[8];
  const float* c3w = (const float*)d_in[9];
  const float* c3b = (const float*)d_in[10];
  const float* bn3g = (const float*)d_in[11];
  const float* bn3b = (const float*)d_in[12];
  const float* pos = (const float*)d_in[13];
  const float* fc1w1 = (const float*)d_in[14];
  const float* fc1b1 = (const float*)d_in[15];
  const float* fc1s1 = (const float*)d_in[16];
  const float* fc1w2 = (const float*)d_in[17];
  const float* fc1b2 = (const float*)d_in[18];
  const float* fc1s2 = (const float*)d_in[19];
  const float* fc2w1 = (const float*)d_in[20];
  const float* fc2b1 = (const float*)d_in[21];
  const float* fc2s1 = (const float*)d_in[22];
  const float* fc2w2 = (const float*)d_in[23];
  const float* fc2b2 = (const float*)d_in[24];
  const float* fc2s2 = (const float*)d_in[25];
  const float* ffnw1 = (const float*)d_in[26];
  const float* ffnb1 = (const float*)d_in[27];
  const float* ffns1 = (const float*)d_in[28];
  const float* ffnw2 = (const float*)d_in[29];
  const float* ffnb2 = (const float*)d_in[30];
  const float* ffns2 = (const float*)d_in[31];
  const float* gcw = (const float*)d_in[32];
  const float* gcb = (const float*)d_in[33];
  const float* gcs = (const float*)d_in[34];
  const float* clsw = (const float*)d_in[35];
  const float* headb = (const float*)d_in[36];
  float* out = (float*)d_out;

  float* ws = (float*)d_ws;
  size_t off = 0;
  auto alloc = [&](size_t n) { float* p = ws + off; off += n; return p; };
  float* WT6 = alloc((size_t)6 * 6 * CC * CC);
  float* GCT = alloc((size_t)6 * 2 * CC * CC);
  float* C1 = alloc((size_t)BB * 160 * 112 * 112);
  float* C2 = alloc((size_t)BB * CC * NN);
  float* C3 = alloc((size_t)BB * CC * NN);
  float* X  = alloc((size_t)RR * CC);
  float* T1 = alloc((size_t)RR * CC);
  float* TMP = alloc((size_t)RR * CC);
  float* T2 = alloc((size_t)RR * CC);
  float* F  = alloc((size_t)RR * CC);
  float* Y  = alloc((size_t)RR * CC);
  float* T4 = alloc((size_t)RR * CC);
  float* T5 = alloc((size_t)RR * CC);
  float* T6 = alloc((size_t)RR * CC);
  float* CAT = alloc((size_t)RR * 2 * CC);
  float* SQ = alloc(RR);
  float* POOL = alloc(BB * CC);
  float* DIST = alloc((size_t)NN * NN);
  int* IDX = (int*)(ws + off);
  off += (size_t)RR * 9;

  {
    size_t tot = (size_t)6 * 6 * CC * CC;
    transpose6<<<dim3((unsigned)((tot + 255) / 256)), 256, 0, stream>>>(
        fc1w1, fc1w2, fc2w1, fc2w2, ffnw1, ffnw2, WT6);
    size_t tg = (size_t)6 * 2 * CC * CC;
    transpose_gc<<<dim3((unsigned)((tg + 255) / 256)), 256, 0, stream>>>(gcw, GCT);
  }

  conv_bn<3, 224, 224, 160, 112, 112, 2, true>
      <<<dim3((BB * 160 * 112 * 112 + 255) / 256), 256, 0, stream>>>(x, c1w, c1b, bn1g, bn1b, C1);
  conv_bn<160, 112, 112, 320, 56, 56, 2, true>
      <<<dim3((BB * 320 * 56 * 56 + 255) / 256), 256, 0, stream>>>(C1, c2w, c2b, bn2g, bn2b, C2);
  conv_bn<320, 56, 56, 320, 56, 56, 1, false>
      <<<dim3((BB * 320 * 56 * 56 + 255) / 256), 256, 0, stream>>>(C2, c3w, c3b, bn3g, bn3b, C3);
  expmap_kernel<<<dim3(RR), CC, 0, stream>>>(C3, pos, X);

  dim3 ggrid(5, 98);
  dim3 pgrid(49, 5, BB);
  for (int l = 0; l < 6; l++) {
    const float* w11 = WT6 + ((size_t)0 * 6 + l) * CC * CC;
    const float* w12 = WT6 + ((size_t)1 * 6 + l) * CC * CC;
    const float* w21 = WT6 + ((size_t)2 * 6 + l) * CC * CC;
    const float* w22 = WT6 + ((size_t)3 * 6 + l) * CC * CC;
    const float* wf1 = WT6 + ((size_t)4 * 6 + l) * CC * CC;
    const float* wf2 = WT6 + ((size_t)5 * 6 + l) * CC * CC;
    const float* wgc = GCT + (size_t)l * 2 * CC * CC;

    // ffn1 (fc1): T2 = LL(LL(X)) + X
    gemm_ll<<<ggrid, 256, 0, stream>>>(X, w11, fc1b1 + l * CC, TMP, RR, CC);
    lorentz_norm<<<RR / 4, 256, 0, stream>>>(TMP, fc1s1, l, nullptr, T1);
    gemm_ll<<<ggrid, 256, 0, stream>>>(T1, w12, fc1b2 + l * CC, TMP, RR, CC);
    lorentz_norm<<<RR / 4, 256, 0, stream>>>(TMP, fc1s2, l, X, T2);

    // f = P(T2)  (reshape-reinterpret (B,N,C)->(B,C,N,1) then transpose)
    pperm_kernel<<<pgrid, 256, 0, stream>>>(T2, nullptr, F);

    // graph conv on F
    sq_kernel<<<RR / 4, 256, 0, stream>>>(F, SQ);
    for (int b = 0; b < BB; b++) {
      dist_gemm<<<dim3(49, 49), 256, 0, stream>>>(F + (size_t)b * NN * CC, SQ + (size_t)b * NN, DIST);
      if (l < 4)
        topk_kernel<9, 1><<<NN / 4, 256, 0, stream>>>(DIST, IDX + (size_t)b * NN * 9);
      else
        topk_kernel<18, 2><<<NN / 4, 256, 0, stream>>>(DIST, IDX + (size_t)b * NN * 9);
    }
    gather_max_cat<<<RR, CC, 0, stream>>>(F, IDX, CAT);
    gemm_ll<<<ggrid, 256, 0, stream>>>(CAT, wgc, gcb + l * CC, TMP, RR, 2 * CC);
    lorentz_norm<<<RR / 4, 256, 0, stream>>>(TMP, gcs, l, nullptr, Y);

    // ffn2 (fc2): T4 = LL(LL(Y)) + Y
    gemm_ll<<<ggrid, 256, 0, stream>>>(Y, w21, fc2b1 + l * CC, TMP, RR, CC);
    lorentz_norm<<<RR / 4, 256, 0, stream>>>(TMP, fc2s1, l, nullptr, T1);
    gemm_ll<<<ggrid, 256, 0, stream>>>(T1, w22, fc2b2 + l * CC, TMP, RR, CC);
    lorentz_norm<<<RR / 4, 256, 0, stream>>>(TMP, fc2s2, l, Y, T4);

    // T5 = P(T4) + X   (reshape + channel-major shortcut, re-viewed as tokens)
    pperm_kernel<<<pgrid, 256, 0, stream>>>(T4, X, T5);

    // ffn3: T6 = LL(LL(T5)) + T5
    gemm_ll<<<ggrid, 256, 0, stream>>>(T5, wf1, ffnb1 + l * CC, TMP, RR, CC);
    lorentz_norm<<<RR / 4, 256, 0, stream>>>(TMP, ffns1, l, nullptr, T1);
    gemm_ll<<<ggrid, 256, 0, stream>>>(T1, wf2, ffnb2 + l * CC, TMP, RR, CC);
    lorentz_norm<<<RR / 4, 256, 0, stream>>>(TMP, ffns2, l, T5, T6);

    // next block token view: X = P(T6)
    pperm_kernel<<<pgrid, 256, 0, stream>>>(T6, nullptr, X);
  }

  hipMemsetAsync(POOL, 0, (size_t)BB * CC * sizeof(float), stream);
  pool_kernel<<<dim3(49, BB), CC, 0, stream>>>(X, POOL);
  head_kernel<<<dim3((BB * 1000 + 255) / 256), 256, 0, stream>>>(POOL, clsw, headb, out);
}

// Round 5
// 4765.002 us; speedup vs baseline: 1.5434x; 1.5434x over previous
//
#include <hip/hip_runtime.h>
#include <cstdint>
#include <cstddef>

constexpr int CC = 320;     // channels
constexpr int NN = 3136;    // tokens (56*56)
constexpr int BB = 2;       // batch
constexpr int RR = BB * NN; // 6272 rows
constexpr float BN_INV_F = 0.9999950000374997f; // 1/sqrt(1+1e-5)

// ---------------- weight transposes: (l, co, ci) -> (l, ci, co) ----------------
__global__ __launch_bounds__(256) void transpose6(
    const float* __restrict__ w0, const float* __restrict__ w1,
    const float* __restrict__ w2, const float* __restrict__ w3,
    const float* __restrict__ w4, const float* __restrict__ w5,
    float* __restrict__ out) {
  size_t e = (size_t)blockIdx.x * 256 + threadIdx.x;
  const size_t per = (size_t)6 * CC * CC;
  if (e >= 6 * per) return;
  int m = (int)(e / per);
  size_t r = e % per;
  int l = (int)(r / (CC * CC));
  int q = (int)(r % (CC * CC));
  int ci = q / CC, co = q % CC;
  const float* src = (m == 0) ? w0 : (m == 1) ? w1 : (m == 2) ? w2
                   : (m == 3) ? w3 : (m == 4) ? w4 : w5;
  out[e] = src[(size_t)l * CC * CC + (size_t)co * CC + ci];
}

__global__ __launch_bounds__(256) void transpose_gc(const float* __restrict__ w,
                                                    float* __restrict__ out) {
  size_t e = (size_t)blockIdx.x * 256 + threadIdx.x;
  const size_t tot = (size_t)6 * 2 * CC * CC;
  if (e >= tot) return;
  int l = (int)(e / (2 * CC * CC));
  int q = (int)(e % (2 * CC * CC));
  int ci = q / CC, co = q % CC; // ci in [0,640)
  out[e] = w[(size_t)l * CC * 2 * CC + (size_t)co * 2 * CC + ci];
}

// ---------------- conv1 direct (Round-2 exact): NCHW -> NCHW, bias+BN+relu ----------------
__global__ __launch_bounds__(256) void conv1_bn(
    const float* __restrict__ x, const float* __restrict__ w,
    const float* __restrict__ cb, const float* __restrict__ g,
    const float* __restrict__ bt, float* __restrict__ out) {
  int t = blockIdx.x * 256 + threadIdx.x;
  if (t >= BB * 160 * 112 * 112) return;
  int ow = t % 112;
  int r = t / 112;
  int oh = r % 112; r /= 112;
  int oc = r % 160;
  int b = r / 160;
  int ih0 = oh * 2 - 1, iw0 = ow * 2 - 1;
  const float* wp = w + (size_t)oc * 3 * 9;
  const float* xb = x + (size_t)b * 3 * 224 * 224;
  float acc = 0.f;
#pragma unroll
  for (int ic = 0; ic < 3; ic++) {
    const float* xc = xb + (size_t)ic * 224 * 224;
    const float* wc = wp + ic * 9;
#pragma unroll
    for (int kh = 0; kh < 3; kh++) {
      int ih = ih0 + kh;
      if (ih < 0 || ih >= 224) continue;
      const float* xr = xc + (size_t)ih * 224;
#pragma unroll
      for (int kw = 0; kw < 3; kw++) {
        int iw = iw0 + kw;
        if (iw < 0 || iw >= 224) continue;
        acc = fmaf(xr[iw], wc[kh * 3 + kw], acc);
      }
    }
  }
  float y = (acc + cb[oc]) * (BN_INV_F * g[oc]) + bt[oc];
  out[t] = fmaxf(y, 0.f);
}

// ---------------- conv2/conv3 fast direct: 1 thread = 1 pixel x 4 oc ----------------
// Preserves Round-2's exact per-output fmaf chain order (ic outer, kh, kw inner,
// in-bounds terms only) => bit-identical outputs. Input/output NCHW.
template <int CIN, int IH, int IW, int S, bool RELU>
__global__ __launch_bounds__(256) void conv_fast(
    const float* __restrict__ x, const float* __restrict__ w,
    const float* __restrict__ cb, const float* __restrict__ g,
    const float* __restrict__ bt, float* __restrict__ out) {
  int p = blockIdx.x * 256 + threadIdx.x; // 0..RR-1 (pixel across batch)
  if (p >= RR) return;
  int oc0 = blockIdx.y * 4; // block-uniform -> weight loads become scalar
  int b = p / 3136, pix = p % 3136;
  int oh = pix / 56, ow = pix % 56;
  int ih0 = S * oh - 1, iw0 = S * ow - 1;
  const float* xb = x + (size_t)b * CIN * IH * IW;
  const float* w0 = w + (size_t)(oc0 + 0) * CIN * 9;
  const float* w1 = w + (size_t)(oc0 + 1) * CIN * 9;
  const float* w2 = w + (size_t)(oc0 + 2) * CIN * 9;
  const float* w3 = w + (size_t)(oc0 + 3) * CIN * 9;
  float a0 = 0.f, a1 = 0.f, a2 = 0.f, a3 = 0.f;
  for (int ic = 0; ic < CIN; ic++) {
    const float* xc = xb + (size_t)ic * IH * IW;
    int wo = ic * 9;
#pragma unroll
    for (int kh = 0; kh < 3; kh++) {
      int ih = ih0 + kh;
      if (ih < 0 || ih >= IH) continue;
      const float* xr = xc + (size_t)ih * IW;
#pragma unroll
      for (int kw = 0; kw < 3; kw++) {
        int iw = iw0 + kw;
        if (iw < 0 || iw >= IW) continue;
        float v = xr[iw];
        int k = wo + kh * 3 + kw;
        a0 = fmaf(v, w0[k], a0);
        a1 = fmaf(v, w1[k], a1);
        a2 = fmaf(v, w2[k], a2);
        a3 = fmaf(v, w3[k], a3);
      }
    }
  }
  float acc[4] = {a0, a1, a2, a3};
#pragma unroll
  for (int q = 0; q < 4; q++) {
    int oc = oc0 + q;
    float y = (acc[q] + cb[oc]) * (BN_INV_F * g[oc]) + bt[oc];
    if (RELU) y = fmaxf(y, 0.f);
    out[((size_t)(b * 320 + oc)) * 3136 + pix] = y;
  }
}

// ---------------- expmap0 over channel dim + pos embed; (B,C,N) -> tokens (B,N,C) ----------------
__global__ __launch_bounds__(CC) void expmap_kernel(const float* __restrict__ h,
                                                    const float* __restrict__ pos,
                                                    float* __restrict__ X) {
  int bn = blockIdx.x;
  int b = bn / NN, n = bn % NN;
  int c = threadIdx.x;
  float u = h[((size_t)(b * CC + c)) * NN + n] + pos[(size_t)c * NN + n];
  float v = (c == 0) ? 0.f : u * u;
#pragma unroll
  for (int o = 32; o > 0; o >>= 1) v += __shfl_down(v, o, 64);
  __shared__ float red[5];
  __shared__ float fac[2];
  if ((c & 63) == 0) red[c >> 6] = v;
  __syncthreads();
  if (c == 0) {
    float s = red[0] + red[1] + red[2] + red[3] + red[4];
    float nrm = sqrtf(fmaxf(s, 1e-8f));
    fac[0] = coshf(nrm);
    fac[1] = sinhf(nrm) / nrm;
  }
  __syncthreads();
  X[(size_t)bn * CC + c] = (c == 0) ? fac[0] : fac[1] * u;
}

// ---------------- P permutation: V[n*C+c] = U[c*N+n]  (+ optional add[n*C+c]) ----------------
__global__ __launch_bounds__(256) void pperm_kernel(const float* __restrict__ U,
                                                    const float* __restrict__ add,
                                                    float* __restrict__ V) {
  __shared__ float t[64][65];
  int b = blockIdx.z;
  int n0 = blockIdx.x * 64;
  int c0 = blockIdx.y * 64;
  const float* Ub = U + (size_t)b * NN * CC;
  float* Vb = V + (size_t)b * NN * CC;
  const float* Ab = add ? add + (size_t)b * NN * CC : nullptr;
  int tx = threadIdx.x & 63;
  int ty = threadIdx.x >> 6; // 0..3
#pragma unroll
  for (int i = 0; i < 16; i++) {
    int c = ty * 16 + i;
    t[c][tx] = Ub[(size_t)(c0 + c) * NN + n0 + tx];
  }
  __syncthreads();
#pragma unroll
  for (int i = 0; i < 16; i++) {
    int n = ty * 16 + i;
    float v = t[tx][n];
    size_t o = (size_t)(n0 + n) * CC + c0 + tx;
    if (Ab) v += Ab[o];
    Vb[o] = v;
  }
}

// ---------------- GEMM: C[M,320] = op(A[M,K]) @ WT[K,320] + bias ----------------
template <bool ARELU>
__global__ __launch_bounds__(256) void gemm_t(const float* __restrict__ A,
                                              const float* __restrict__ BW,
                                              const float* __restrict__ bias,
                                              float* __restrict__ C, int M, int K) {
  __shared__ float As[16][68];
  __shared__ float Bs[16][64];
  int tid = threadIdx.x;
  int n0 = blockIdx.x * 64;
  int m0 = blockIdx.y * 64;
  int lm = tid >> 2;
  int lk = (tid & 3) << 2;
  int bk = tid >> 4;
  int bn = (tid & 15) << 2;
  int tm = (tid >> 4) << 2;
  int tn = (tid & 15) << 2;
  float acc[4][4] = {};
  for (int k0 = 0; k0 < K; k0 += 16) {
    float4 a = *(const float4*)(A + (size_t)(m0 + lm) * K + k0 + lk);
    if (ARELU) {
      a.x = fmaxf(a.x, 0.f); a.y = fmaxf(a.y, 0.f);
      a.z = fmaxf(a.z, 0.f); a.w = fmaxf(a.w, 0.f);
    }
    As[lk + 0][lm] = a.x; As[lk + 1][lm] = a.y;
    As[lk + 2][lm] = a.z; As[lk + 3][lm] = a.w;
    *(float4*)&Bs[bk][bn] = *(const float4*)(BW + (size_t)(k0 + bk) * CC + n0 + bn);
    __syncthreads();
#pragma unroll
    for (int k = 0; k < 16; k++) {
      float4 av = *(const float4*)&As[k][tm];
      float4 bv = *(const float4*)&Bs[k][tn];
      float aa[4] = {av.x, av.y, av.z, av.w};
      float bb[4] = {bv.x, bv.y, bv.z, bv.w};
#pragma unroll
      for (int i = 0; i < 4; i++)
#pragma unroll
        for (int j = 0; j < 4; j++) acc[i][j] = fmaf(aa[i], bb[j], acc[i][j]);
    }
    __syncthreads();
  }
  float4 bv = *(const float4*)(bias + n0 + tn);
  float bb[4] = {bv.x, bv.y, bv.z, bv.w};
#pragma unroll
  for (int i = 0; i < 4; i++) {
    float4 o;
    o.x = acc[i][0] + bb[0]; o.y = acc[i][1] + bb[1];
    o.z = acc[i][2] + bb[2]; o.w = acc[i][3] + bb[3];
    *(float4*)(C + (size_t)(m0 + tm + i) * CC + n0 + tn) = o;
  }
}

// ---------------- Lorentz row normalization (+ optional residual) ----------------
__global__ __launch_bounds__(256) void lorentz_norm(const float* __restrict__ Y,
                                                    const float* __restrict__ logs, int l,
                                                    const float* __restrict__ res1,
                                                    float* __restrict__ out) {
  int lane = threadIdx.x & 63;
  size_t row = (size_t)blockIdx.x * 4 + (threadIdx.x >> 6);
  const float* y = Y + row * CC;
  float v[5];
  float ss = 0.f;
#pragma unroll
  for (int q = 0; q < 5; q++) {
    v[q] = y[q * 64 + lane];
    float z = v[q] * v[q];
    if (q == 0 && lane == 0) z = 0.f;
    ss += z;
  }
#pragma unroll
  for (int o = 32; o > 0; o >>= 1) ss += __shfl_down(ss, o, 64);
  ss = __shfl(ss, 0, 64);
  float y0 = __shfl(v[0], 0, 64);
  float scale = expf(logs[l]);
  float tmv = scale / (1.f + expf(-y0)) + 1.1f;
  float rf = sqrtf((tmv * tmv - 1.f) / fmaxf(ss, 1e-8f));
#pragma unroll
  for (int q = 0; q < 5; q++) {
    int c = q * 64 + lane;
    float o = (c == 0) ? tmv : v[q] * rf;
    if (res1) o += res1[row * CC + c];
    out[row * CC + c] = o;
  }
}

// ---------------- per-row squared norms ----------------
__global__ __launch_bounds__(256) void sq_kernel(const float* __restrict__ Y,
                                                 float* __restrict__ sq) {
  int lane = threadIdx.x & 63;
  size_t row = (size_t)blockIdx.x * 4 + (threadIdx.x >> 6);
  const float* y = Y + row * CC;
  float ss = 0.f;
#pragma unroll
  for (int q = 0; q < 5; q++) {
    float v = y[q * 64 + lane];
    ss += v * v;
  }
#pragma unroll
  for (int o = 32; o > 0; o >>= 1) ss += __shfl_down(ss, o, 64);
  if (lane == 0) sq[row] = ss;
}

// ---------------- distance tile: D[i,j] = sq_i + sq_j - 2 * Y_i . Y_j ----------------
__global__ __launch_bounds__(256) void dist_gemm(const float* __restrict__ Y,
                                                 const float* __restrict__ sq,
                                                 float* __restrict__ D) {
  __shared__ float As[16][68];
  __shared__ float Bs[16][68];
  int tid = threadIdx.x;
  int j0 = blockIdx.x * 64;
  int i0 = blockIdx.y * 64;
  int lr = tid >> 2;
  int lk = (tid & 3) << 2;
  int tm = (tid >> 4) << 2;
  int tn = (tid & 15) << 2;
  float acc[4][4] = {};
  for (int k0 = 0; k0 < CC; k0 += 16) {
    float4 a = *(const float4*)(Y + (size_t)(i0 + lr) * CC + k0 + lk);
    As[lk + 0][lr] = a.x; As[lk + 1][lr] = a.y;
    As[lk + 2][lr] = a.z; As[lk + 3][lr] = a.w;
    float4 b = *(const float4*)(Y + (size_t)(j0 + lr) * CC + k0 + lk);
    Bs[lk + 0][lr] = b.x; Bs[lk + 1][lr] = b.y;
    Bs[lk + 2][lr] = b.z; Bs[lk + 3][lr] = b.w;
    __syncthreads();
#pragma unroll
    for (int k = 0; k < 16; k++) {
      float4 av = *(const float4*)&As[k][tm];
      float4 bv = *(const float4*)&Bs[k][tn];
      float aa[4] = {av.x, av.y, av.z, av.w};
      float bb[4] = {bv.x, bv.y, bv.z, bv.w};
#pragma unroll
      for (int i = 0; i < 4; i++)
#pragma unroll
        for (int j = 0; j < 4; j++) acc[i][j] = fmaf(aa[i], bb[j], acc[i][j]);
    }
    __syncthreads();
  }
  float sqi[4], sqj[4];
#pragma unroll
  for (int i = 0; i < 4; i++) sqi[i] = sq[i0 + tm + i];
#pragma unroll
  for (int j = 0; j < 4; j++) sqj[j] = sq[j0 + tn + j];
#pragma unroll
  for (int i = 0; i < 4; i++) {
    float4 o;
    o.x = sqi[i] + sqj[0] - 2.f * acc[i][0];
    o.y = sqi[i] + sqj[1] - 2.f * acc[i][1];
    o.z = sqi[i] + sqj[2] - 2.f * acc[i][2];
    o.w = sqi[i] + sqj[3] - 2.f * acc[i][3];
    *(float4*)(D + (size_t)(i0 + tm + i) * NN + j0 + tn) = o;
  }
}

// ---------------- exact top-k (jax tie-break: dist asc, index asc), wave per row ----------------
template <int KT, int DIL>
__global__ __launch_bounds__(256) void topk_kernel(const float* __restrict__ D,
                                                   int* __restrict__ idxout) {
  int lane = threadIdx.x & 63;
  int row = blockIdx.x * 4 + (threadIdx.x >> 6); // row within one batch, [0, NN)
  const float* d = D + (size_t)row * NN;
  float ld[KT];
  int li[KT];
#pragma unroll
  for (int q = 0; q < KT; q++) { ld[q] = 3.4e38f; li[q] = 0x7FFFFFFF; }
  for (int t = 0; t < NN / 64; t++) {
    int j = t * 64 + lane;
    float x = d[j];
    if (x < ld[KT - 1]) {
      ld[KT - 1] = x;
      li[KT - 1] = j;
#pragma unroll
      for (int p = KT - 1; p > 0; p--) {
        if (ld[p] < ld[p - 1]) {
          float tf = ld[p]; ld[p] = ld[p - 1]; ld[p - 1] = tf;
          int ti = li[p]; li[p] = li[p - 1]; li[p - 1] = ti;
        }
      }
    }
  }
#pragma unroll 1
  for (int q = 0; q < KT; q++) {
    float bd = ld[0];
    int bi = li[0];
#pragma unroll
    for (int s = 32; s > 0; s >>= 1) {
      float od = __shfl_xor(bd, s, 64);
      int oi = __shfl_xor(bi, s, 64);
      if (od < bd || (od == bd && oi < bi)) { bd = od; bi = oi; }
    }
    if (ld[0] == bd && li[0] == bi) {
#pragma unroll
      for (int p = 0; p < KT - 1; p++) { ld[p] = ld[p + 1]; li[p] = li[p + 1]; }
      ld[KT - 1] = 3.4e38f;
      li[KT - 1] = 0x7FFFFFFF;
    }
    if (lane == 0 && (q % DIL) == 0) idxout[(size_t)row * 9 + q / DIL] = bi;
  }
}

// ---------------- neighbor max + concat [f, max_j f_j - f_i] ----------------
__global__ __launch_bounds__(CC) void gather_max_cat(const float* __restrict__ Y,
                                                     const int* __restrict__ idx,
                                                     float* __restrict__ cat) {
  int bn = blockIdx.x;
  int c = threadIdx.x;
  int b = bn / NN;
  float yc = Y[(size_t)bn * CC + c];
  const int* ip = idx + (size_t)bn * 9;
  float mx = -3.4e38f;
#pragma unroll
  for (int q = 0; q < 9; q++) {
    int j = ip[q];
    mx = fmaxf(mx, Y[((size_t)b * NN + j) * CC + c]);
  }
  cat[(size_t)bn * 2 * CC + c] = yc;
  cat[(size_t)bn * 2 * CC + CC + c] = mx - yc;
}

// ---------------- pooling + head ----------------
__global__ __launch_bounds__(CC) void pool_kernel(const float* __restrict__ X,
                                                  float* __restrict__ pooled) {
  int b = blockIdx.y;
  int chunk = blockIdx.x;
  int c = threadIdx.x;
  const float* p = X + ((size_t)b * NN + (size_t)chunk * 64) * CC + c;
  float s = 0.f;
#pragma unroll
  for (int q = 0; q < 64; q++) s += p[(size_t)q * CC];
  atomicAdd(&pooled[b * CC + c], s);
}

__global__ __launch_bounds__(256) void head_kernel(const float* __restrict__ pooled,
                                                   const float* __restrict__ clsw,
                                                   const float* __restrict__ hb,
                                                   float* __restrict__ out) {
  int t = blockIdx.x * 256 + threadIdx.x;
  if (t >= BB * 1000) return;
  int b = t / 1000, k = t % 1000;
  const float* pw = pooled + b * CC;
  const float* cw = clsw + (size_t)k * CC;
  float acc = 0.f;
  for (int c = 0; c < CC; c++) {
    float sgn = (c == 0) ? -1.f : 1.f;
    acc = fmaf(pw[c] * sgn, cw[c], acc);
  }
  out[t] = 2.f + 2.f * (acc * (1.f / 3136.f)) + hb[k];
}

// ---------------- launch ----------------
extern "C" void kernel_launch(void* const* d_in, const int* in_sizes, int n_in,
                              void* d_out, int out_size, void* d_ws, size_t ws_size,
                              hipStream_t stream) {
  const float* x = (const float*)d_in[0];
  const float* c1w = (const float*)d_in[1];
  const float* c1b = (const float*)d_in[2];
  const float* bn1g = (const float*)d_in[3];
  const float* bn1b = (const float*)d_in[4];
  const float* c2w = (const float*)d_in[5];
  const float* c2b = (const float*)d_in[6];
  const float* bn2g = (const float*)d_in[7];
  const float* bn2b = (const float*)d_in[8];
  const float* c3w = (const float*)d_in[9];
  const float* c3b = (const float*)d_in[10];
  const float* bn3g = (const float*)d_in[11];
  const float* bn3b = (const float*)d_in[12];
  const float* pos = (const float*)d_in[13];
  const float* fc1w1 = (const float*)d_in[14];
  const float* fc1b1 = (const float*)d_in[15];
  const float* fc1s1 = (const float*)d_in[16];
  const float* fc1w2 = (const float*)d_in[17];
  const float* fc1b2 = (const float*)d_in[18];
  const float* fc1s2 = (const float*)d_in[19];
  const float* fc2w1 = (const float*)d_in[20];
  const float* fc2b1 = (const float*)d_in[21];
  const float* fc2s1 = (const float*)d_in[22];
  const float* fc2w2 = (const float*)d_in[23];
  const float* fc2b2 = (const float*)d_in[24];
  const float* fc2s2 = (const float*)d_in[25];
  const float* ffnw1 = (const float*)d_in[26];
  const float* ffnb1 = (const float*)d_in[27];
  const float* ffns1 = (const float*)d_in[28];
  const float* ffnw2 = (const float*)d_in[29];
  const float* ffnb2 = (const float*)d_in[30];
  const float* ffns2 = (const float*)d_in[31];
  const float* gcw = (const float*)d_in[32];
  const float* gcb = (const float*)d_in[33];
  const float* gcs = (const float*)d_in[34];
  const float* clsw = (const float*)d_in[35];
  const float* headb = (const float*)d_in[36];
  float* out = (float*)d_out;

  float* ws = (float*)d_ws;
  size_t off = 0;
  auto alloc = [&](size_t n) { float* p = ws + off; off += n; return p; };
  float* WT6 = alloc((size_t)6 * 6 * CC * CC);
  float* GCT = alloc((size_t)6 * 2 * CC * CC);
  float* C1 = alloc((size_t)BB * 160 * 112 * 112); // NCHW, post-relu
  float* C2 = alloc((size_t)BB * CC * NN);         // NCHW, post-relu
  float* C3 = alloc((size_t)BB * CC * NN);         // NCHW
  float* X  = alloc((size_t)RR * CC);
  float* T1 = alloc((size_t)RR * CC);
  float* TMP = alloc((size_t)RR * CC);
  float* T2 = alloc((size_t)RR * CC);
  float* F  = alloc((size_t)RR * CC);
  float* Y  = alloc((size_t)RR * CC);
  float* T4 = alloc((size_t)RR * CC);
  float* T5 = alloc((size_t)RR * CC);
  float* T6 = alloc((size_t)RR * CC);
  float* CAT = alloc((size_t)RR * 2 * CC);
  float* DIST = alloc((size_t)NN * NN);
  float* SQ = alloc(RR);
  float* POOL = alloc(BB * CC);
  int* IDX = (int*)(ws + off);
  off += (size_t)RR * 9;

  {
    size_t tot = (size_t)6 * 6 * CC * CC;
    transpose6<<<dim3((unsigned)((tot + 255) / 256)), 256, 0, stream>>>(
        fc1w1, fc1w2, fc2w1, fc2w2, ffnw1, ffnw2, WT6);
    size_t tg = (size_t)6 * 2 * CC * CC;
    transpose_gc<<<dim3((unsigned)((tg + 255) / 256)), 256, 0, stream>>>(gcw, GCT);
  }

  // ---- stem: direct convs with Round-2-exact accumulation order ----
  conv1_bn<<<dim3((BB * 160 * 112 * 112 + 255) / 256), 256, 0, stream>>>(
      x, c1w, c1b, bn1g, bn1b, C1);
  conv_fast<160, 112, 112, 2, true><<<dim3((RR + 255) / 256, 80), 256, 0, stream>>>(
      C1, c2w, c2b, bn2g, bn2b, C2);
  conv_fast<320, 56, 56, 1, false><<<dim3((RR + 255) / 256, 80), 256, 0, stream>>>(
      C2, c3w, c3b, bn3g, bn3b, C3);
  expmap_kernel<<<dim3(RR), CC, 0, stream>>>(C3, pos, X);

  dim3 ggrid(5, 98);
  dim3 pgrid(49, 5, BB);
  for (int l = 0; l < 6; l++) {
    const float* w11 = WT6 + ((size_t)0 * 6 + l) * CC * CC;
    const float* w12 = WT6 + ((size_t)1 * 6 + l) * CC * CC;
    const float* w21 = WT6 + ((size_t)2 * 6 + l) * CC * CC;
    const float* w22 = WT6 + ((size_t)3 * 6 + l) * CC * CC;
    const float* wf1 = WT6 + ((size_t)4 * 6 + l) * CC * CC;
    const float* wf2 = WT6 + ((size_t)5 * 6 + l) * CC * CC;
    const float* wgc = GCT + (size_t)l * 2 * CC * CC;

    // ffn1 (fc1): T2 = LL(LL(X)) + X
    gemm_t<true><<<ggrid, 256, 0, stream>>>(X, w11, fc1b1 + l * CC, TMP, RR, CC);
    lorentz_norm<<<RR / 4, 256, 0, stream>>>(TMP, fc1s1, l, nullptr, T1);
    gemm_t<true><<<ggrid, 256, 0, stream>>>(T1, w12, fc1b2 + l * CC, TMP, RR, CC);
    lorentz_norm<<<RR / 4, 256, 0, stream>>>(TMP, fc1s2, l, X, T2);

    // f = P(T2)
    pperm_kernel<<<pgrid, 256, 0, stream>>>(T2, nullptr, F);

    // graph conv on F
    sq_kernel<<<RR / 4, 256, 0, stream>>>(F, SQ);
    for (int b = 0; b < BB; b++) {
      dist_gemm<<<dim3(49, 49), 256, 0, stream>>>(F + (size_t)b * NN * CC, SQ + (size_t)b * NN, DIST);
      if (l < 4)
        topk_kernel<9, 1><<<NN / 4, 256, 0, stream>>>(DIST, IDX + (size_t)b * NN * 9);
      else
        topk_kernel<18, 2><<<NN / 4, 256, 0, stream>>>(DIST, IDX + (size_t)b * NN * 9);
    }
    gather_max_cat<<<RR, CC, 0, stream>>>(F, IDX, CAT);
    gemm_t<true><<<ggrid, 256, 0, stream>>>(CAT, wgc, gcb + l * CC, TMP, RR, 2 * CC);
    lorentz_norm<<<RR / 4, 256, 0, stream>>>(TMP, gcs, l, nullptr, Y);

    // ffn2 (fc2): T4 = LL(LL(Y)) + Y
    gemm_t<true><<<ggrid, 256, 0, stream>>>(Y, w21, fc2b1 + l * CC, TMP, RR, CC);
    lorentz_norm<<<RR / 4, 256, 0, stream>>>(TMP, fc2s1, l, nullptr, T1);
    gemm_t<true><<<ggrid, 256, 0, stream>>>(T1, w22, fc2b2 + l * CC, TMP, RR, CC);
    lorentz_norm<<<RR / 4, 256, 0, stream>>>(TMP, fc2s2, l, Y, T4);

    // T5 = P(T4) + X
    pperm_kernel<<<pgrid, 256, 0, stream>>>(T4, X, T5);

    // ffn3: T6 = LL(LL(T5)) + T5
    gemm_t<true><<<ggrid, 256, 0, stream>>>(T5, wf1, ffnb1 + l * CC, TMP, RR, CC);
    lorentz_norm<<<RR / 4, 256, 0, stream>>>(TMP, ffns1, l, nullptr, T1);
    gemm_t<true><<<ggrid, 256, 0, stream>>>(T1, wf2, ffnb2 + l * CC, TMP, RR, CC);
    lorentz_norm<<<RR / 4, 256, 0, stream>>>(TMP, ffns2, l, T5, T6);

    // next block token view: X = P(T6)
    pperm_kernel<<<pgrid, 256, 0, stream>>>(T6, nullptr, X);
  }

  hipMemsetAsync(POOL, 0, (size_t)BB * CC * sizeof(float), stream);
  pool_kernel<<<dim3(49, BB), CC, 0, stream>>>(X, POOL);
  head_kernel<<<dim3((BB * 1000 + 255) / 256), 256, 0, stream>>>(POOL, clsw, headb, out);
}

// Round 6
// 4749.928 us; speedup vs baseline: 1.5483x; 1.0032x over previous
//
#include <hip/hip_runtime.h>
#include <cstdint>
#include <cstddef>

constexpr int CC = 320;     // channels
constexpr int NN = 3136;    // tokens (56*56)
constexpr int BB = 2;       // batch
constexpr int RR = BB * NN; // 6272 rows
constexpr float BN_INV_F = 0.9999950000374997f; // 1/sqrt(1+1e-5)

// ---------------- weight transposes: (l, co, ci) -> (l, ci, co) ----------------
__global__ __launch_bounds__(256) void transpose6(
    const float* __restrict__ w0, const float* __restrict__ w1,
    const float* __restrict__ w2, const float* __restrict__ w3,
    const float* __restrict__ w4, const float* __restrict__ w5,
    float* __restrict__ out) {
  size_t e = (size_t)blockIdx.x * 256 + threadIdx.x;
  const size_t per = (size_t)6 * CC * CC;
  if (e >= 6 * per) return;
  int m = (int)(e / per);
  size_t r = e % per;
  int l = (int)(r / (CC * CC));
  int q = (int)(r % (CC * CC));
  int ci = q / CC, co = q % CC;
  const float* src = (m == 0) ? w0 : (m == 1) ? w1 : (m == 2) ? w2
                   : (m == 3) ? w3 : (m == 4) ? w4 : w5;
  out[e] = src[(size_t)l * CC * CC + (size_t)co * CC + ci];
}

__global__ __launch_bounds__(256) void transpose_gc(const float* __restrict__ w,
                                                    float* __restrict__ out) {
  size_t e = (size_t)blockIdx.x * 256 + threadIdx.x;
  const size_t tot = (size_t)6 * 2 * CC * CC;
  if (e >= tot) return;
  int l = (int)(e / (2 * CC * CC));
  int q = (int)(e % (2 * CC * CC));
  int ci = q / CC, co = q % CC; // ci in [0,640)
  out[e] = w[(size_t)l * CC * 2 * CC + (size_t)co * 2 * CC + ci];
}

// ---------------- conv1 direct (Round-2 exact): NCHW -> NCHW, bias+BN+relu ----------------
__global__ __launch_bounds__(256) void conv1_bn(
    const float* __restrict__ x, const float* __restrict__ w,
    const float* __restrict__ cb, const float* __restrict__ g,
    const float* __restrict__ bt, float* __restrict__ out) {
  int t = blockIdx.x * 256 + threadIdx.x;
  if (t >= BB * 160 * 112 * 112) return;
  int ow = t % 112;
  int r = t / 112;
  int oh = r % 112; r /= 112;
  int oc = r % 160;
  int b = r / 160;
  int ih0 = oh * 2 - 1, iw0 = ow * 2 - 1;
  const float* wp = w + (size_t)oc * 3 * 9;
  const float* xb = x + (size_t)b * 3 * 224 * 224;
  float acc = 0.f;
#pragma unroll
  for (int ic = 0; ic < 3; ic++) {
    const float* xc = xb + (size_t)ic * 224 * 224;
    const float* wc = wp + ic * 9;
#pragma unroll
    for (int kh = 0; kh < 3; kh++) {
      int ih = ih0 + kh;
      if (ih < 0 || ih >= 224) continue;
      const float* xr = xc + (size_t)ih * 224;
#pragma unroll
      for (int kw = 0; kw < 3; kw++) {
        int iw = iw0 + kw;
        if (iw < 0 || iw >= 224) continue;
        acc = fmaf(xr[iw], wc[kh * 3 + kw], acc);
      }
    }
  }
  float y = (acc + cb[oc]) * (BN_INV_F * g[oc]) + bt[oc];
  out[t] = fmaxf(y, 0.f);
}

// ---------------- conv2/conv3 fast direct: 1 thread = 1 pixel x 8 oc ----------------
// Preserves Round-2's exact per-output fmaf chain order (ic outer, kh, kw inner,
// in-bounds terms only) => bit-identical outputs. Input/output NCHW.
template <int CIN, int IH, int IW, int S, bool RELU>
__global__ __launch_bounds__(256) void conv_fast(
    const float* __restrict__ x, const float* __restrict__ w,
    const float* __restrict__ cb, const float* __restrict__ g,
    const float* __restrict__ bt, float* __restrict__ out) {
  int p = blockIdx.x * 256 + threadIdx.x; // 0..RR-1 (pixel across batch)
  if (p >= RR) return;
  int oc0 = blockIdx.y * 8; // block-uniform -> weight loads become scalar
  int b = p / 3136, pix = p % 3136;
  int oh = pix / 56, ow = pix % 56;
  int ih0 = S * oh - 1, iw0 = S * ow - 1;
  const float* xb = x + (size_t)b * CIN * IH * IW;
  const float* wp[8];
#pragma unroll
  for (int q = 0; q < 8; q++) wp[q] = w + (size_t)(oc0 + q) * CIN * 9;
  float acc[8] = {};
  for (int ic = 0; ic < CIN; ic++) {
    const float* xc = xb + (size_t)ic * IH * IW;
    int wo = ic * 9;
#pragma unroll
    for (int kh = 0; kh < 3; kh++) {
      int ih = ih0 + kh;
      if (ih < 0 || ih >= IH) continue;
      const float* xr = xc + (size_t)ih * IW;
#pragma unroll
      for (int kw = 0; kw < 3; kw++) {
        int iw = iw0 + kw;
        if (iw < 0 || iw >= IW) continue;
        float v = xr[iw];
        int k = wo + kh * 3 + kw;
#pragma unroll
        for (int q = 0; q < 8; q++) acc[q] = fmaf(v, wp[q][k], acc[q]);
      }
    }
  }
#pragma unroll
  for (int q = 0; q < 8; q++) {
    int oc = oc0 + q;
    float y = (acc[q] + cb[oc]) * (BN_INV_F * g[oc]) + bt[oc];
    if (RELU) y = fmaxf(y, 0.f);
    out[((size_t)(b * 320 + oc)) * 3136 + pix] = y;
  }
}

// ---------------- expmap0 over channel dim + pos embed; (B,C,N) -> tokens (B,N,C) ----------------
__global__ __launch_bounds__(CC) void expmap_kernel(const float* __restrict__ h,
                                                    const float* __restrict__ pos,
                                                    float* __restrict__ X) {
  int bn = blockIdx.x;
  int b = bn / NN, n = bn % NN;
  int c = threadIdx.x;
  float u = h[((size_t)(b * CC + c)) * NN + n] + pos[(size_t)c * NN + n];
  float v = (c == 0) ? 0.f : u * u;
#pragma unroll
  for (int o = 32; o > 0; o >>= 1) v += __shfl_down(v, o, 64);
  __shared__ float red[5];
  __shared__ float fac[2];
  if ((c & 63) == 0) red[c >> 6] = v;
  __syncthreads();
  if (c == 0) {
    float s = red[0] + red[1] + red[2] + red[3] + red[4];
    float nrm = sqrtf(fmaxf(s, 1e-8f));
    fac[0] = coshf(nrm);
    fac[1] = sinhf(nrm) / nrm;
  }
  __syncthreads();
  X[(size_t)bn * CC + c] = (c == 0) ? fac[0] : fac[1] * u;
}

// ---------------- P permutation: V[n*C+c] = U[c*N+n]  (+ optional add[n*C+c]) ----------------
__global__ __launch_bounds__(256) void pperm_kernel(const float* __restrict__ U,
                                                    const float* __restrict__ add,
                                                    float* __restrict__ V) {
  __shared__ float t[64][65];
  int b = blockIdx.z;
  int n0 = blockIdx.x * 64;
  int c0 = blockIdx.y * 64;
  const float* Ub = U + (size_t)b * NN * CC;
  float* Vb = V + (size_t)b * NN * CC;
  const float* Ab = add ? add + (size_t)b * NN * CC : nullptr;
  int tx = threadIdx.x & 63;
  int ty = threadIdx.x >> 6; // 0..3
#pragma unroll
  for (int i = 0; i < 16; i++) {
    int c = ty * 16 + i;
    t[c][tx] = Ub[(size_t)(c0 + c) * NN + n0 + tx];
  }
  __syncthreads();
#pragma unroll
  for (int i = 0; i < 16; i++) {
    int n = ty * 16 + i;
    float v = t[tx][n];
    size_t o = (size_t)(n0 + n) * CC + c0 + tx;
    if (Ab) v += Ab[o];
    Vb[o] = v;
  }
}

// ---------------- GEMM: C[M,320] = op(A[M,K]) @ WT[K,320] + bias ----------------
// 32x64 tile, 128 threads, 4x4 microtile per thread. Same per-output K-order as
// the 64x64 version => bit-identical results.
template <bool ARELU>
__global__ __launch_bounds__(128) void gemm_t(const float* __restrict__ A,
                                              const float* __restrict__ BW,
                                              const float* __restrict__ bias,
                                              float* __restrict__ C, int M, int K) {
  __shared__ float As[16][36];
  __shared__ float Bs[16][64];
  int tid = threadIdx.x;
  int n0 = blockIdx.x * 64;
  int m0 = blockIdx.y * 32;
  int lm = tid >> 2;          // 0..31
  int lk = (tid & 3) << 2;    // 0,4,8,12
  int bk = tid >> 4;          // 0..7
  int bn = (tid & 15) << 2;   // 0..60
  int tm = (tid >> 4) << 2;   // 0..28
  int tn = (tid & 15) << 2;   // 0..60
  float acc[4][4] = {};
  for (int k0 = 0; k0 < K; k0 += 16) {
    float4 a = *(const float4*)(A + (size_t)(m0 + lm) * K + k0 + lk);
    if (ARELU) {
      a.x = fmaxf(a.x, 0.f); a.y = fmaxf(a.y, 0.f);
      a.z = fmaxf(a.z, 0.f); a.w = fmaxf(a.w, 0.f);
    }
    As[lk + 0][lm] = a.x; As[lk + 1][lm] = a.y;
    As[lk + 2][lm] = a.z; As[lk + 3][lm] = a.w;
    *(float4*)&Bs[bk][bn] = *(const float4*)(BW + (size_t)(k0 + bk) * CC + n0 + bn);
    *(float4*)&Bs[bk + 8][bn] = *(const float4*)(BW + (size_t)(k0 + bk + 8) * CC + n0 + bn);
    __syncthreads();
#pragma unroll
    for (int k = 0; k < 16; k++) {
      float4 av = *(const float4*)&As[k][tm];
      float4 bv = *(const float4*)&Bs[k][tn];
      float aa[4] = {av.x, av.y, av.z, av.w};
      float bb[4] = {bv.x, bv.y, bv.z, bv.w};
#pragma unroll
      for (int i = 0; i < 4; i++)
#pragma unroll
        for (int j = 0; j < 4; j++) acc[i][j] = fmaf(aa[i], bb[j], acc[i][j]);
    }
    __syncthreads();
  }
  float4 bv = *(const float4*)(bias + n0 + tn);
  float bb[4] = {bv.x, bv.y, bv.z, bv.w};
#pragma unroll
  for (int i = 0; i < 4; i++) {
    float4 o;
    o.x = acc[i][0] + bb[0]; o.y = acc[i][1] + bb[1];
    o.z = acc[i][2] + bb[2]; o.w = acc[i][3] + bb[3];
    *(float4*)(C + (size_t)(m0 + tm + i) * CC + n0 + tn) = o;
  }
}

// ---------------- Lorentz row normalization (+ optional residual) ----------------
__global__ __launch_bounds__(256) void lorentz_norm(const float* __restrict__ Y,
                                                    const float* __restrict__ logs, int l,
                                                    const float* __restrict__ res1,
                                                    float* __restrict__ out) {
  int lane = threadIdx.x & 63;
  size_t row = (size_t)blockIdx.x * 4 + (threadIdx.x >> 6);
  const float* y = Y + row * CC;
  float v[5];
  float ss = 0.f;
#pragma unroll
  for (int q = 0; q < 5; q++) {
    v[q] = y[q * 64 + lane];
    float z = v[q] * v[q];
    if (q == 0 && lane == 0) z = 0.f;
    ss += z;
  }
#pragma unroll
  for (int o = 32; o > 0; o >>= 1) ss += __shfl_down(ss, o, 64);
  ss = __shfl(ss, 0, 64);
  float y0 = __shfl(v[0], 0, 64);
  float scale = expf(logs[l]);
  float tmv = scale / (1.f + expf(-y0)) + 1.1f;
  float rf = sqrtf((tmv * tmv - 1.f) / fmaxf(ss, 1e-8f));
#pragma unroll
  for (int q = 0; q < 5; q++) {
    int c = q * 64 + lane;
    float o = (c == 0) ? tmv : v[q] * rf;
    if (res1) o += res1[row * CC + c];
    out[row * CC + c] = o;
  }
}

// ---------------- per-row squared norms ----------------
__global__ __launch_bounds__(256) void sq_kernel(const float* __restrict__ Y,
                                                 float* __restrict__ sq) {
  int lane = threadIdx.x & 63;
  size_t row = (size_t)blockIdx.x * 4 + (threadIdx.x >> 6);
  const float* y = Y + row * CC;
  float ss = 0.f;
#pragma unroll
  for (int q = 0; q < 5; q++) {
    float v = y[q * 64 + lane];
    ss += v * v;
  }
#pragma unroll
  for (int o = 32; o > 0; o >>= 1) ss += __shfl_down(ss, o, 64);
  if (lane == 0) sq[row] = ss;
}

// ---------------- distance tile: D[i,j] = sq_i + sq_j - 2 * Y_i . Y_j ----------------
__global__ __launch_bounds__(256) void dist_gemm(const float* __restrict__ Y,
                                                 const float* __restrict__ sq,
                                                 float* __restrict__ D) {
  __shared__ float As[16][68];
  __shared__ float Bs[16][68];
  int tid = threadIdx.x;
  int j0 = blockIdx.x * 64;
  int i0 = blockIdx.y * 64;
  int lr = tid >> 2;
  int lk = (tid & 3) << 2;
  int tm = (tid >> 4) << 2;
  int tn = (tid & 15) << 2;
  float acc[4][4] = {};
  for (int k0 = 0; k0 < CC; k0 += 16) {
    float4 a = *(const float4*)(Y + (size_t)(i0 + lr) * CC + k0 + lk);
    As[lk + 0][lr] = a.x; As[lk + 1][lr] = a.y;
    As[lk + 2][lr] = a.z; As[lk + 3][lr] = a.w;
    float4 b = *(const float4*)(Y + (size_t)(j0 + lr) * CC + k0 + lk);
    Bs[lk + 0][lr] = b.x; Bs[lk + 1][lr] = b.y;
    Bs[lk + 2][lr] = b.z; Bs[lk + 3][lr] = b.w;
    __syncthreads();
#pragma unroll
    for (int k = 0; k < 16; k++) {
      float4 av = *(const float4*)&As[k][tm];
      float4 bv = *(const float4*)&Bs[k][tn];
      float aa[4] = {av.x, av.y, av.z, av.w};
      float bb[4] = {bv.x, bv.y, bv.z, bv.w};
#pragma unroll
      for (int i = 0; i < 4; i++)
#pragma unroll
        for (int j = 0; j < 4; j++) acc[i][j] = fmaf(aa[i], bb[j], acc[i][j]);
    }
    __syncthreads();
  }
  float sqi[4], sqj[4];
#pragma unroll
  for (int i = 0; i < 4; i++) sqi[i] = sq[i0 + tm + i];
#pragma unroll
  for (int j = 0; j < 4; j++) sqj[j] = sq[j0 + tn + j];
#pragma unroll
  for (int i = 0; i < 4; i++) {
    float4 o;
    o.x = sqi[i] + sqj[0] - 2.f * acc[i][0];
    o.y = sqi[i] + sqj[1] - 2.f * acc[i][1];
    o.z = sqi[i] + sqj[2] - 2.f * acc[i][2];
    o.w = sqi[i] + sqj[3] - 2.f * acc[i][3];
    *(float4*)(D + (size_t)(i0 + tm + i) * NN + j0 + tn) = o;
  }
}

// ---------------- exact top-k (jax tie-break: dist asc, index asc), wave per row ----------------
template <int KT, int DIL>
__global__ __launch_bounds__(256) void topk_kernel(const float* __restrict__ D,
                                                   int* __restrict__ idxout) {
  int lane = threadIdx.x & 63;
  int row = blockIdx.x * 4 + (threadIdx.x >> 6); // row within one batch, [0, NN)
  const float* d = D + (size_t)row * NN;
  float ld[KT];
  int li[KT];
#pragma unroll
  for (int q = 0; q < KT; q++) { ld[q] = 3.4e38f; li[q] = 0x7FFFFFFF; }
  for (int t = 0; t < NN / 64; t++) {
    int j = t * 64 + lane;
    float x = d[j];
    if (x < ld[KT - 1]) {
      ld[KT - 1] = x;
      li[KT - 1] = j;
#pragma unroll
      for (int p = KT - 1; p > 0; p--) {
        if (ld[p] < ld[p - 1]) {
          float tf = ld[p]; ld[p] = ld[p - 1]; ld[p - 1] = tf;
          int ti = li[p]; li[p] = li[p - 1]; li[p - 1] = ti;
        }
      }
    }
  }
#pragma unroll 1
  for (int q = 0; q < KT; q++) {
    float bd = ld[0];
    int bi = li[0];
#pragma unroll
    for (int s = 32; s > 0; s >>= 1) {
      float od = __shfl_xor(bd, s, 64);
      int oi = __shfl_xor(bi, s, 64);
      if (od < bd || (od == bd && oi < bi)) { bd = od; bi = oi; }
    }
    if (ld[0] == bd && li[0] == bi) {
#pragma unroll
      for (int p = 0; p < KT - 1; p++) { ld[p] = ld[p + 1]; li[p] = li[p + 1]; }
      ld[KT - 1] = 3.4e38f;
      li[KT - 1] = 0x7FFFFFFF;
    }
    if (lane == 0 && (q % DIL) == 0) idxout[(size_t)row * 9 + q / DIL] = bi;
  }
}

// ---------------- neighbor max + concat [f, max_j f_j - f_i] ----------------
__global__ __launch_bounds__(CC) void gather_max_cat(const float* __restrict__ Y,
                                                     const int* __restrict__ idx,
                                                     float* __restrict__ cat) {
  int bn = blockIdx.x;
  int c = threadIdx.x;
  int b = bn / NN;
  float yc = Y[(size_t)bn * CC + c];
  const int* ip = idx + (size_t)bn * 9;
  float mx = -3.4e38f;
#pragma unroll
  for (int q = 0; q < 9; q++) {
    int j = ip[q];
    mx = fmaxf(mx, Y[((size_t)b * NN + j) * CC + c]);
  }
  cat[(size_t)bn * 2 * CC + c] = yc;
  cat[(size_t)bn * 2 * CC + CC + c] = mx - yc;
}

// ---------------- pooling + head ----------------
__global__ __launch_bounds__(CC) void pool_kernel(const float* __restrict__ X,
                                                  float* __restrict__ pooled) {
  int b = blockIdx.y;
  int chunk = blockIdx.x;
  int c = threadIdx.x;
  const float* p = X + ((size_t)b * NN + (size_t)chunk * 64) * CC + c;
  float s = 0.f;
#pragma unroll
  for (int q = 0; q < 64; q++) s += p[(size_t)q * CC];
  atomicAdd(&pooled[b * CC + c], s);
}

__global__ __launch_bounds__(256) void head_kernel(const float* __restrict__ pooled,
                                                   const float* __restrict__ clsw,
                                                   const float* __restrict__ hb,
                                                   float* __restrict__ out) {
  int t = blockIdx.x * 256 + threadIdx.x;
  if (t >= BB * 1000) return;
  int b = t / 1000, k = t % 1000;
  const float* pw = pooled + b * CC;
  const float* cw = clsw + (size_t)k * CC;
  float acc = 0.f;
  for (int c = 0; c < CC; c++) {
    float sgn = (c == 0) ? -1.f : 1.f;
    acc = fmaf(pw[c] * sgn, cw[c], acc);
  }
  out[t] = 2.f + 2.f * (acc * (1.f / 3136.f)) + hb[k];
}

// ---------------- launch ----------------
extern "C" void kernel_launch(void* const* d_in, const int* in_sizes, int n_in,
                              void* d_out, int out_size, void* d_ws, size_t ws_size,
                              hipStream_t stream) {
  const float* x = (const float*)d_in[0];
  const float* c1w = (const float*)d_in[1];
  const float* c1b = (const float*)d_in[2];
  const float* bn1g = (const float*)d_in[3];
  const float* bn1b = (const float*)d_in[4];
  const float* c2w = (const float*)d_in[5];
  const float* c2b = (const float*)d_in[6];
  const float* bn2g = (const float*)d_in[7];
  const float* bn2b = (const float*)d_in[8];
  const float* c3w = (const float*)d_in[9];
  const float* c3b = (const float*)d_in[10];
  const float* bn3g = (const float*)d_in[11];
  const float* bn3b = (const float*)d_in[12];
  const float* pos = (const float*)d_in[13];
  const float* fc1w1 = (const float*)d_in[14];
  const float* fc1b1 = (const float*)d_in[15];
  const float* fc1s1 = (const float*)d_in[16];
  const float* fc1w2 = (const float*)d_in[17];
  const float* fc1b2 = (const float*)d_in[18];
  const float* fc1s2 = (const float*)d_in[19];
  const float* fc2w1 = (const float*)d_in[20];
  const float* fc2b1 = (const float*)d_in[21];
  const float* fc2s1 = (const float*)d_in[22];
  const float* fc2w2 = (const float*)d_in[23];
  const float* fc2b2 = (const float*)d_in[24];
  const float* fc2s2 = (const float*)d_in[25];
  const float* ffnw1 = (const float*)d_in[26];
  const float* ffnb1 = (const float*)d_in[27];
  const float* ffns1 = (const float*)d_in[28];
  const float* ffnw2 = (const float*)d_in[29];
  const float* ffnb2 = (const float*)d_in[30];
  const float* ffns2 = (const float*)d_in[31];
  const float* gcw = (const float*)d_in[32];
  const float* gcb = (const float*)d_in[33];
  const float* gcs = (const float*)d_in[34];
  const float* clsw = (const float*)d_in[35];
  const float* headb = (const float*)d_in[36];
  float* out = (float*)d_out;

  float* ws = (float*)d_ws;
  size_t off = 0;
  auto alloc = [&](size_t n) { float* p = ws + off; off += n; return p; };
  float* WT6 = alloc((size_t)6 * 6 * CC * CC);
  float* GCT = alloc((size_t)6 * 2 * CC * CC);
  float* C1 = alloc((size_t)BB * 160 * 112 * 112); // NCHW, post-relu
  float* C2 = alloc((size_t)BB * CC * NN);         // NCHW, post-relu
  float* C3 = alloc((size_t)BB * CC * NN);         // NCHW
  float* X  = alloc((size_t)RR * CC);
  float* T1 = alloc((size_t)RR * CC);
  float* TMP = alloc((size_t)RR * CC);
  float* T2 = alloc((size_t)RR * CC);
  float* F  = alloc((size_t)RR * CC);
  float* Y  = alloc((size_t)RR * CC);
  float* T4 = alloc((size_t)RR * CC);
  float* T5 = alloc((size_t)RR * CC);
  float* T6 = alloc((size_t)RR * CC);
  float* CAT = alloc((size_t)RR * 2 * CC);
  float* DIST = alloc((size_t)NN * NN);
  float* SQ = alloc(RR);
  float* POOL = alloc(BB * CC);
  int* IDX = (int*)(ws + off);
  off += (size_t)RR * 9;

  {
    size_t tot = (size_t)6 * 6 * CC * CC;
    transpose6<<<dim3((unsigned)((tot + 255) / 256)), 256, 0, stream>>>(
        fc1w1, fc1w2, fc2w1, fc2w2, ffnw1, ffnw2, WT6);
    size_t tg = (size_t)6 * 2 * CC * CC;
    transpose_gc<<<dim3((unsigned)((tg + 255) / 256)), 256, 0, stream>>>(gcw, GCT);
  }

  // ---- stem: direct convs with Round-2-exact accumulation order ----
  conv1_bn<<<dim3((BB * 160 * 112 * 112 + 255) / 256), 256, 0, stream>>>(
      x, c1w, c1b, bn1g, bn1b, C1);
  conv_fast<160, 112, 112, 2, true><<<dim3((RR + 255) / 256, 40), 256, 0, stream>>>(
      C1, c2w, c2b, bn2g, bn2b, C2);
  conv_fast<320, 56, 56, 1, false><<<dim3((RR + 255) / 256, 40), 256, 0, stream>>>(
      C2, c3w, c3b, bn3g, bn3b, C3);
  expmap_kernel<<<dim3(RR), CC, 0, stream>>>(C3, pos, X);

  dim3 ggrid(5, 196);   // 32x64 tiles, 128 threads
  dim3 pgrid(49, 5, BB);
  for (int l = 0; l < 6; l++) {
    const float* w11 = WT6 + ((size_t)0 * 6 + l) * CC * CC;
    const float* w12 = WT6 + ((size_t)1 * 6 + l) * CC * CC;
    const float* w21 = WT6 + ((size_t)2 * 6 + l) * CC * CC;
    const float* w22 = WT6 + ((size_t)3 * 6 + l) * CC * CC;
    const float* wf1 = WT6 + ((size_t)4 * 6 + l) * CC * CC;
    const float* wf2 = WT6 + ((size_t)5 * 6 + l) * CC * CC;
    const float* wgc = GCT + (size_t)l * 2 * CC * CC;

    // ffn1 (fc1): T2 = LL(LL(X)) + X
    gemm_t<true><<<ggrid, 128, 0, stream>>>(X, w11, fc1b1 + l * CC, TMP, RR, CC);
    lorentz_norm<<<RR / 4, 256, 0, stream>>>(TMP, fc1s1, l, nullptr, T1);
    gemm_t<true><<<ggrid, 128, 0, stream>>>(T1, w12, fc1b2 + l * CC, TMP, RR, CC);
    lorentz_norm<<<RR / 4, 256, 0, stream>>>(TMP, fc1s2, l, X, T2);

    // f = P(T2)
    pperm_kernel<<<pgrid, 256, 0, stream>>>(T2, nullptr, F);

    // graph conv on F
    sq_kernel<<<RR / 4, 256, 0, stream>>>(F, SQ);
    for (int b = 0; b < BB; b++) {
      dist_gemm<<<dim3(49, 49), 256, 0, stream>>>(F + (size_t)b * NN * CC, SQ + (size_t)b * NN, DIST);
      if (l < 4)
        topk_kernel<9, 1><<<NN / 4, 256, 0, stream>>>(DIST, IDX + (size_t)b * NN * 9);
      else
        topk_kernel<18, 2><<<NN / 4, 256, 0, stream>>>(DIST, IDX + (size_t)b * NN * 9);
    }
    gather_max_cat<<<RR, CC, 0, stream>>>(F, IDX, CAT);
    gemm_t<true><<<ggrid, 128, 0, stream>>>(CAT, wgc, gcb + l * CC, TMP, RR, 2 * CC);
    lorentz_norm<<<RR / 4, 256, 0, stream>>>(TMP, gcs, l, nullptr, Y);

    // ffn2 (fc2): T4 = LL(LL(Y)) + Y
    gemm_t<true><<<ggrid, 128, 0, stream>>>(Y, w21, fc2b1 + l * CC, TMP, RR, CC);
    lorentz_norm<<<RR / 4, 256, 0, stream>>>(TMP, fc2s1, l, nullptr, T1);
    gemm_t<true><<<ggrid, 128, 0, stream>>>(T1, w22, fc2b2 + l * CC, TMP, RR, CC);
    lorentz_norm<<<RR / 4, 256, 0, stream>>>(TMP, fc2s2, l, Y, T4);

    // T5 = P(T4) + X
    pperm_kernel<<<pgrid, 256, 0, stream>>>(T4, X, T5);

    // ffn3: T6 = LL(LL(T5)) + T5
    gemm_t<true><<<ggrid, 128, 0, stream>>>(T5, wf1, ffnb1 + l * CC, TMP, RR, CC);
    lorentz_norm<<<RR / 4, 256, 0, stream>>>(TMP, ffns1, l, nullptr, T1);
    gemm_t<true><<<ggrid, 128, 0, stream>>>(T1, wf2, ffnb2 + l * CC, TMP, RR, CC);
    lorentz_norm<<<RR / 4, 256, 0, stream>>>(TMP, ffns2, l, T5, T6);

    // next block token view: X = P(T6)
    pperm_kernel<<<pgrid, 256, 0, stream>>>(T6, nullptr, X);
  }

  hipMemsetAsync(POOL, 0, (size_t)BB * CC * sizeof(float), stream);
  pool_kernel<<<dim3(49, BB), CC, 0, stream>>>(X, POOL);
  head_kernel<<<dim3((BB * 1000 + 255) / 256), 256, 0, stream>>>(POOL, clsw, headb, out);
}